// Round 1
// baseline (203.869 us; speedup 1.0000x reference)
//
#include <hip/hip_runtime.h>
#include <math.h>

#define B_N 32768
#define NCLS 1000
#define NSAMP 1000000
#define NTAB 31

__constant__ float c_conf[NTAB] = {
    0.9991138577461243f, 0.8724386692047119f, 0.8048540353775024f, 0.7398145198822021f,
    0.6715637445449829f, 0.5973713397979736f, 0.5154045820236206f, 0.42423248291015625f,
    0.3226756751537323f, 0.20976418256759644f, 0.08473344892263412f, -0.05296758562326431f,
    -0.2036692053079605f, -0.3674810528755188f, -0.5443023443222046f, -0.7338425517082214f,
    -0.9356498718261719f, -1.149145483970642f, -1.3736592531204224f, -1.6084641218185425f,
    -1.8528070449829102f, -2.1059343814849854f, -2.367111921310425f, -2.6356399059295654f,
    -2.910861015319824f, -3.1921679973602295f, -3.479003667831421f, -3.770861864089966f,
    -4.067285060882568f, -4.367861747741699f, -4.67222261428833f};

// Precomputed from the LOSS_DIV_WD table:
//   LOG0 = ln(-0.7357585932962737 + 0.750256) = -4.23378549
//   LOG30 = ln(999.249744 + 0.750256) = ln(1000) = 6.90775528
//   LOG_STEP = (LOG30-LOG0)/2 = 5.57077038 ; LOG_OFFSET = LOG0+LOG_STEP = 1.33698489
#define LOG_OFFSET 1.3369849f
#define INV_LOG_STEP 0.17950834f
#define LN_SMOOTH -0.10536052f  /* ln(0.9) */

__device__ __forceinline__ float optimal_conf(float l) {
    float ln = (logf(l + 0.750256f) - LOG_OFFSET) * INV_LOG_STEP;
    if (ln != ln) ln = -1.0f;                       // NaN (log of negative) -> left border
    float ix = fminf(fmaxf((ln + 1.0f) * 0.5f * (NTAB - 1), 0.0f), (float)(NTAB - 1));
    float i0f = floorf(ix);
    float frac = ix - i0f;
    int i0 = (int)i0f;
    int i1 = min(i0 + 1, NTAB - 1);
    float r = c_conf[i0] * (1.0f - frac) + c_conf[i1] * frac;
    return expf(r);
}

// One WAVE per row: no __syncthreads, no LDS, 4 independent float4 loads per lane.
// 256-thread block handles 4 rows.
__global__ __launch_bounds__(256) void ce_loss_kernel(
    const float* __restrict__ preds, const int* __restrict__ labels,
    const int* __restrict__ indices, float* __restrict__ loss,
    float* __restrict__ ins_sum, float* __restrict__ ins_cnt,
    float* __restrict__ cls_sum, float* __restrict__ cls_cnt,
    float* __restrict__ out)
{
    const int t = threadIdx.x;
    const int wave = t >> 6, lane = t & 63;
    const int row = blockIdx.x * 4 + wave;

    // fold the scalar-output zeroing into this kernel (runs before conf_reduce in stream order)
    if (blockIdx.x == 0 && t == 0) *out = 0.0f;

    const float4* p = (const float4*)(preds + (size_t)row * NCLS);

    // NCLS = 1000 = 250 float4; lanes cover f4-indices lane, lane+64, lane+128, lane+192
    const float NEG_INF = -INFINITY;
    float4 v0 = p[lane];
    float4 v1 = p[lane + 64];
    float4 v2 = p[lane + 128];
    float4 v3 = make_float4(NEG_INF, NEG_INF, NEG_INF, NEG_INF);
    if (lane < 58) v3 = p[lane + 192];   // f4-index 192+lane < 250

    // wave max (all lanes end with M)
    float m = fmaxf(fmaxf(fmaxf(v0.x, v0.y), fmaxf(v0.z, v0.w)),
                    fmaxf(fmaxf(v1.x, v1.y), fmaxf(v1.z, v1.w)));
    m = fmaxf(m, fmaxf(fmaxf(v2.x, v2.y), fmaxf(v2.z, v2.w)));
    m = fmaxf(m, fmaxf(fmaxf(v3.x, v3.y), fmaxf(v3.z, v3.w)));
    #pragma unroll
    for (int off = 32; off > 0; off >>= 1) m = fmaxf(m, __shfl_xor(m, off, 64));

    // wave sum of exp(x - M); -inf pads contribute exp(-inf)=0
    float s = expf(v0.x - m) + expf(v0.y - m) + expf(v0.z - m) + expf(v0.w - m);
    s += expf(v1.x - m) + expf(v1.y - m) + expf(v1.z - m) + expf(v1.w - m);
    s += expf(v2.x - m) + expf(v2.y - m) + expf(v2.z - m) + expf(v2.w - m);
    s += expf(v3.x - m) + expf(v3.y - m) + expf(v3.z - m) + expf(v3.w - m);
    #pragma unroll
    for (int off = 32; off > 0; off >>= 1) s += __shfl_xor(s, off, 64);

    if (lane == 0) {
        const int lab = labels[row];
        const float l = logf(s) + m - preds[(size_t)row * NCLS + lab];  // L1-hot re-read
        loss[row] = l;
        const int idx = indices[row];
        atomicAdd(&ins_sum[idx], l);
        atomicAdd(&ins_cnt[idx], 1.0f);
        atomicAdd(&cls_sum[lab], l);
        atomicAdd(&cls_cnt[lab], 1.0f);
    }
}

// Per-sample EMA + conf interp + mean reduction.
__global__ __launch_bounds__(256) void conf_reduce_kernel(
    const float* __restrict__ loss, const int* __restrict__ labels,
    const int* __restrict__ indices,
    const float* __restrict__ mem_ins, const float* __restrict__ mem_cls,
    const float* __restrict__ ins_sum, const float* __restrict__ ins_cnt,
    const float* __restrict__ cls_sum, const float* __restrict__ cls_cnt,
    float* __restrict__ out)
{
    const int i = blockIdx.x * 256 + threadIdx.x;
    float val = 0.0f;
    if (i < B_N) {
        const float l = loss[i];
        const int idx = indices[i];
        const int lab = labels[i];

        const float ci = ins_cnt[idx];                 // >= 1 for gathered bins
        const float mean_i = ins_sum[idx] / ci;
        const float ai = expf(ci * LN_SMOOTH);         // 0.9^cnt
        const float sl_i = ai * mem_ins[idx] + (1.0f - ai) * mean_i;

        const float cc = cls_cnt[lab];
        const float mean_c = cls_sum[lab] / cc;
        const float ac = expf(cc * LN_SMOOTH);
        const float sl_c = ac * mem_cls[lab] + (1.0f - ac) * mean_c;

        const float conf = optimal_conf(sl_i) * optimal_conf(sl_c);
        val = l * conf * (1.0f / (float)B_N);
    }
    #pragma unroll
    for (int off = 32; off > 0; off >>= 1) val += __shfl_down(val, off, 64);
    __shared__ float sm[4];
    const int wave = threadIdx.x >> 6, lane = threadIdx.x & 63;
    if (lane == 0) sm[wave] = val;
    __syncthreads();
    if (threadIdx.x == 0) atomicAdd(out, sm[0] + sm[1] + sm[2] + sm[3]);
}

extern "C" void kernel_launch(void* const* d_in, const int* in_sizes, int n_in,
                              void* d_out, int out_size, void* d_ws, size_t ws_size,
                              hipStream_t stream) {
    const float* preds   = (const float*)d_in[0];
    const float* mem_ins = (const float*)d_in[1];
    const float* mem_cls = (const float*)d_in[2];
    const int*   labels  = (const int*)d_in[3];
    const int*   indices = (const int*)d_in[4];
    float* out = (float*)d_out;

    float* loss    = (float*)d_ws;            // B_N
    float* ins_sum = loss + B_N;              // NSAMP
    float* ins_cnt = ins_sum + NSAMP;         // NSAMP
    float* cls_sum = ins_cnt + NSAMP;         // NCLS
    float* cls_cnt = cls_sum + NCLS;          // NCLS

    // zero the contiguous bin-aggregate region (out is zeroed inside ce_loss_kernel)
    hipMemsetAsync(ins_sum, 0, (size_t)(2 * NSAMP + 2 * NCLS) * sizeof(float), stream);

    ce_loss_kernel<<<B_N / 4, 256, 0, stream>>>(preds, labels, indices, loss,
                                                ins_sum, ins_cnt, cls_sum, cls_cnt, out);
    conf_reduce_kernel<<<(B_N + 255) / 256, 256, 0, stream>>>(
        loss, labels, indices, mem_ins, mem_cls,
        ins_sum, ins_cnt, cls_sum, cls_cnt, out);
}

// Round 2
// 199.638 us; speedup vs baseline: 1.0212x; 1.0212x over previous
//
#include <hip/hip_runtime.h>
#include <math.h>

#define B_N 32768
#define NCLS 1000
#define NSAMP 1000000
#define NTAB 31

__constant__ float c_conf[NTAB] = {
    0.9991138577461243f, 0.8724386692047119f, 0.8048540353775024f, 0.7398145198822021f,
    0.6715637445449829f, 0.5973713397979736f, 0.5154045820236206f, 0.42423248291015625f,
    0.3226756751537323f, 0.20976418256759644f, 0.08473344892263412f, -0.05296758562326431f,
    -0.2036692053079605f, -0.3674810528755188f, -0.5443023443222046f, -0.7338425517082214f,
    -0.9356498718261719f, -1.149145483970642f, -1.3736592531204224f, -1.6084641218185425f,
    -1.8528070449829102f, -2.1059343814849854f, -2.367111921310425f, -2.6356399059295654f,
    -2.910861015319824f, -3.1921679973602295f, -3.479003667831421f, -3.770861864089966f,
    -4.067285060882568f, -4.367861747741699f, -4.67222261428833f};

// Precomputed from the LOSS_DIV_WD table:
//   LOG0 = ln(-0.7357585932962737 + 0.750256) = -4.23378549
//   LOG30 = ln(999.249744 + 0.750256) = ln(1000) = 6.90775528
//   LOG_STEP = (LOG30-LOG0)/2 = 5.57077038 ; LOG_OFFSET = LOG0+LOG_STEP = 1.33698489
#define LOG_OFFSET 1.3369849f
#define INV_LOG_STEP 0.17950834f
#define LN_SMOOTH -0.10536052f  /* ln(0.9) */

__device__ __forceinline__ float optimal_conf(float l) {
    // __logf: native v_log_f32. neg -> NaN (caught below); 0 -> -inf (clamps to ix=0).
    float ln = (__logf(l + 0.750256f) - LOG_OFFSET) * INV_LOG_STEP;
    if (ln != ln) ln = -1.0f;                       // NaN (log of negative) -> left border
    float ix = fminf(fmaxf((ln + 1.0f) * 0.5f * (NTAB - 1), 0.0f), (float)(NTAB - 1));
    float i0f = floorf(ix);
    float frac = ix - i0f;
    int i0 = (int)i0f;
    int i1 = min(i0 + 1, NTAB - 1);
    float r = c_conf[i0] * (1.0f - frac) + c_conf[i1] * frac;
    return __expf(r);
}

// One WAVE per row: no __syncthreads, no LDS, 4 independent float4 loads per lane.
// 256-thread block handles 4 rows. Native exp/log (v_exp_f32/v_log_f32) to stay
// under the HBM roofline instead of VALU-bound on ocml expf.
__global__ __launch_bounds__(256) void ce_loss_kernel(
    const float* __restrict__ preds, const int* __restrict__ labels,
    const int* __restrict__ indices, float* __restrict__ loss,
    float* __restrict__ ins_sum, float* __restrict__ ins_cnt,
    float* __restrict__ cls_sum, float* __restrict__ cls_cnt,
    float* __restrict__ out)
{
    const int t = threadIdx.x;
    const int wave = t >> 6, lane = t & 63;
    const int row = blockIdx.x * 4 + wave;

    // fold the scalar-output zeroing into this kernel (runs before conf_reduce in stream order)
    if (blockIdx.x == 0 && t == 0) *out = 0.0f;

    // prefetch the per-row scalars early so they're in flight during the reductions
    const int lab = labels[row];
    const int idx = indices[row];

    const float4* p = (const float4*)(preds + (size_t)row * NCLS);

    // NCLS = 1000 = 250 float4; lanes cover f4-indices lane, lane+64, lane+128, lane+192
    const float NEG_INF = -INFINITY;
    float4 v0 = p[lane];
    float4 v1 = p[lane + 64];
    float4 v2 = p[lane + 128];
    float4 v3 = make_float4(NEG_INF, NEG_INF, NEG_INF, NEG_INF);
    if (lane < 58) v3 = p[lane + 192];   // f4-index 192+lane < 250

    // wave max (all lanes end with M)
    float m = fmaxf(fmaxf(fmaxf(v0.x, v0.y), fmaxf(v0.z, v0.w)),
                    fmaxf(fmaxf(v1.x, v1.y), fmaxf(v1.z, v1.w)));
    m = fmaxf(m, fmaxf(fmaxf(v2.x, v2.y), fmaxf(v2.z, v2.w)));
    m = fmaxf(m, fmaxf(fmaxf(v3.x, v3.y), fmaxf(v3.z, v3.w)));
    #pragma unroll
    for (int off = 32; off > 0; off >>= 1) m = fmaxf(m, __shfl_xor(m, off, 64));

    // wave sum of exp(x - M); -inf pads contribute __expf(-inf)=0
    float s = __expf(v0.x - m) + __expf(v0.y - m) + __expf(v0.z - m) + __expf(v0.w - m);
    s += __expf(v1.x - m) + __expf(v1.y - m) + __expf(v1.z - m) + __expf(v1.w - m);
    s += __expf(v2.x - m) + __expf(v2.y - m) + __expf(v2.z - m) + __expf(v2.w - m);
    s += __expf(v3.x - m) + __expf(v3.y - m) + __expf(v3.z - m) + __expf(v3.w - m);
    #pragma unroll
    for (int off = 32; off > 0; off >>= 1) s += __shfl_xor(s, off, 64);

    if (lane == 0) {
        const float l = __logf(s) + m - preds[(size_t)row * NCLS + lab];  // L1-hot re-read
        loss[row] = l;
        atomicAdd(&ins_sum[idx], l);
        atomicAdd(&ins_cnt[idx], 1.0f);
        atomicAdd(&cls_sum[lab], l);
        atomicAdd(&cls_cnt[lab], 1.0f);
    }
}

// Per-sample EMA + conf interp + mean reduction.
__global__ __launch_bounds__(256) void conf_reduce_kernel(
    const float* __restrict__ loss, const int* __restrict__ labels,
    const int* __restrict__ indices,
    const float* __restrict__ mem_ins, const float* __restrict__ mem_cls,
    const float* __restrict__ ins_sum, const float* __restrict__ ins_cnt,
    const float* __restrict__ cls_sum, const float* __restrict__ cls_cnt,
    float* __restrict__ out)
{
    const int i = blockIdx.x * 256 + threadIdx.x;
    float val = 0.0f;
    if (i < B_N) {
        const float l = loss[i];
        const int idx = indices[i];
        const int lab = labels[i];

        const float ci = ins_cnt[idx];                 // >= 1 for gathered bins
        const float mean_i = ins_sum[idx] / ci;
        const float ai = __expf(ci * LN_SMOOTH);       // 0.9^cnt
        const float sl_i = ai * mem_ins[idx] + (1.0f - ai) * mean_i;

        const float cc = cls_cnt[lab];
        const float mean_c = cls_sum[lab] / cc;
        const float ac = __expf(cc * LN_SMOOTH);
        const float sl_c = ac * mem_cls[lab] + (1.0f - ac) * mean_c;

        const float conf = optimal_conf(sl_i) * optimal_conf(sl_c);
        val = l * conf * (1.0f / (float)B_N);
    }
    #pragma unroll
    for (int off = 32; off > 0; off >>= 1) val += __shfl_down(val, off, 64);
    __shared__ float sm[4];
    const int wave = threadIdx.x >> 6, lane = threadIdx.x & 63;
    if (lane == 0) sm[wave] = val;
    __syncthreads();
    if (threadIdx.x == 0) atomicAdd(out, sm[0] + sm[1] + sm[2] + sm[3]);
}

extern "C" void kernel_launch(void* const* d_in, const int* in_sizes, int n_in,
                              void* d_out, int out_size, void* d_ws, size_t ws_size,
                              hipStream_t stream) {
    const float* preds   = (const float*)d_in[0];
    const float* mem_ins = (const float*)d_in[1];
    const float* mem_cls = (const float*)d_in[2];
    const int*   labels  = (const int*)d_in[3];
    const int*   indices = (const int*)d_in[4];
    float* out = (float*)d_out;

    float* loss    = (float*)d_ws;            // B_N
    float* ins_sum = loss + B_N;              // NSAMP
    float* ins_cnt = ins_sum + NSAMP;         // NSAMP
    float* cls_sum = ins_cnt + NSAMP;         // NCLS
    float* cls_cnt = cls_sum + NCLS;          // NCLS

    // zero the contiguous bin-aggregate region (out is zeroed inside ce_loss_kernel)
    hipMemsetAsync(ins_sum, 0, (size_t)(2 * NSAMP + 2 * NCLS) * sizeof(float), stream);

    ce_loss_kernel<<<B_N / 4, 256, 0, stream>>>(preds, labels, indices, loss,
                                                ins_sum, ins_cnt, cls_sum, cls_cnt, out);
    conf_reduce_kernel<<<(B_N + 255) / 256, 256, 0, stream>>>(
        loss, labels, indices, mem_ins, mem_cls,
        ins_sum, ins_cnt, cls_sum, cls_cnt, out);
}